// Round 5
// baseline (137.627 us; speedup 1.0000x reference)
//
#include <hip/hip_runtime.h>
#include <hip/hip_bf16.h>

#define B_ 2048
#define D_ 17
#define H_ 8
#define HID_ 256
#define OUT_ 23
#define XROW 8721       /* 513*17 floats per batch */

__device__ __forceinline__ float4 ld4u(const float* p) {   // 4B-aligned 16B load
  float4 v; __builtin_memcpy(&v, p, 16); return v;
}

// ---------------- Kernel 1: register-streaming attention -> comb (B x 26) ----------------
// Block 512 = 8 waves = 2 batches; each batch split over 4 waves x 128-row quarter.
// Lane = (head = l&7, rowgroup = l>>3); step s covers contiguous rows [q*128+8s, +8).
// Monotone mask (row dead iff idx >= len) => ballot early-exit skips dead tail LOADS.
__global__ __launch_bounds__(512, 6) void attn_comb_kernel(
    const float* __restrict__ x,
    const float* __restrict__ Wk, const float* __restrict__ bk,
    const float* __restrict__ Wv, const float* __restrict__ bv,
    const float* __restrict__ q,
    const float* __restrict__ Wo, const float* __restrict__ bo,
    float* __restrict__ comb)
{
  __shared__ float s_qk[H_][20];           // padded
  __shared__ float s_ch[H_];
  __shared__ float s_part[8][H_][18];      // per-wave per-head (den, acc[17])
  __shared__ float s_swn[2][H_][D_];
  __shared__ float s_agg[2][H_ * D_];
  __shared__ float s_wp[2][136];

  const int t = threadIdx.x;

  // ---- fold q into Wk: qk[h][d] = sum_e Wk[h,e,d] q[h,e]; ch[h] = bk[h]·q[h]
  if (t < H_ * D_) {
    const int h = t / D_, dd = t - h * D_;
    float s = 0.f;
    #pragma unroll
    for (int e = 0; e < D_; ++e) s = fmaf(Wk[h*289 + e*D_ + dd], q[h*D_ + e], s);
    s_qk[h][dd] = s;
  }
  if (t < H_) {
    float s = 0.f;
    #pragma unroll
    for (int e = 0; e < D_; ++e) s = fmaf(bk[t*D_ + e], q[t*D_ + e], s);
    s_ch[t] = s;
  }
  __syncthreads();

  const int w    = t >> 6;          // wave 0..7
  const int lane = t & 63;
  const int bb   = w >> 2;          // batch within block (0,1)
  const int qtr  = w & 3;           // row quarter (128 rows)
  const int h    = lane & 7;
  const int rg   = lane >> 3;       // rowgroup 0..7
  const int b    = blockIdx.x * 2 + bb;

  float qk[D_];
  #pragma unroll
  for (int d = 0; d < D_; ++d) qk[d] = s_qk[h][d];
  const float chr = s_ch[h];

  const float* rb = x + (size_t)b * XROW + D_ + (size_t)(qtr * 128 + rg) * D_;

  float den = 0.f;
  float acc[D_];
  #pragma unroll
  for (int d = 0; d < D_; ++d) acc[d] = 0.f;

  float4 a0, a1, a2, a3; float a4;     // buffer A
  float4 c0, c1, c2, c3; float c4;     // buffer C

  auto loadA = [&](int S) {
    const float* rp = rb + S * 136;    // step stride = 8 rows * 17
    a0 = ld4u(rp); a1 = ld4u(rp + 4); a2 = ld4u(rp + 8); a3 = ld4u(rp + 12); a4 = rp[16];
  };
  auto loadC = [&](int S) {
    const float* rp = rb + S * 136;
    c0 = ld4u(rp); c1 = ld4u(rp + 4); c2 = ld4u(rp + 8); c3 = ld4u(rp + 12); c4 = rp[16];
  };
  auto comp = [&](const float4& v0, const float4& v1, const float4& v2, const float4& v3, float v4) {
    float sc = chr;
    sc = fmaf(qk[0],  v0.x, sc); sc = fmaf(qk[1],  v0.y, sc);
    sc = fmaf(qk[2],  v0.z, sc); sc = fmaf(qk[3],  v0.w, sc);
    sc = fmaf(qk[4],  v1.x, sc); sc = fmaf(qk[5],  v1.y, sc);
    sc = fmaf(qk[6],  v1.z, sc); sc = fmaf(qk[7],  v1.w, sc);
    sc = fmaf(qk[8],  v2.x, sc); sc = fmaf(qk[9],  v2.y, sc);
    sc = fmaf(qk[10], v2.z, sc); sc = fmaf(qk[11], v2.w, sc);
    sc = fmaf(qk[12], v3.x, sc); sc = fmaf(qk[13], v3.y, sc);
    sc = fmaf(qk[14], v3.z, sc); sc = fmaf(qk[15], v3.w, sc);
    sc = fmaf(qk[16], v4, sc);
    // masked rows are exact zeros; live word0==0 has P~1e-45
    const float p = (v0.x != 0.f) ? __expf(sc) : 0.f;
    den += p;
    acc[0]  = fmaf(p, v0.x, acc[0]);  acc[1]  = fmaf(p, v0.y, acc[1]);
    acc[2]  = fmaf(p, v0.z, acc[2]);  acc[3]  = fmaf(p, v0.w, acc[3]);
    acc[4]  = fmaf(p, v1.x, acc[4]);  acc[5]  = fmaf(p, v1.y, acc[5]);
    acc[6]  = fmaf(p, v1.z, acc[6]);  acc[7]  = fmaf(p, v1.w, acc[7]);
    acc[8]  = fmaf(p, v2.x, acc[8]);  acc[9]  = fmaf(p, v2.y, acc[9]);
    acc[10] = fmaf(p, v2.z, acc[10]); acc[11] = fmaf(p, v2.w, acc[11]);
    acc[12] = fmaf(p, v3.x, acc[12]); acc[13] = fmaf(p, v3.y, acc[13]);
    acc[14] = fmaf(p, v3.z, acc[14]); acc[15] = fmaf(p, v3.w, acc[15]);
    acc[16] = fmaf(p, v4, acc[16]);
  };

  loadA(0);
  #pragma unroll 1
  for (int s = 0; s < 16; s += 2) {
    loadC(s + 1);                                   // prefetch next chunk
    if (__ballot(a0.x != 0.f) == 0ull) break;       // all 8 rows dead -> tail dead
    comp(a0, a1, a2, a3, a4);
    if (s + 2 < 16) loadA(s + 2);
    if (__ballot(c0.x != 0.f) == 0ull) break;
    comp(c0, c1, c2, c3, c4);
  }

  // ---- in-wave reduce over rowgroups (lanes with same head)
  #pragma unroll
  for (int m = 8; m <= 32; m <<= 1) {
    den += __shfl_xor(den, m, 64);
    #pragma unroll
    for (int d = 0; d < D_; ++d) acc[d] += __shfl_xor(acc[d], m, 64);
  }
  if (lane < 8) {
    s_part[w][lane][0] = den;
    #pragma unroll
    for (int d = 0; d < D_; ++d) s_part[w][lane][1 + d] = acc[d];
  }
  __syncthreads();

  // ---- per-batch finish: threads [fb*256, fb*256+256)
  const int fb = t >> 8;
  const int u0 = t & 255;
  const int bf = blockIdx.x * 2 + fb;
  if (u0 < 136) {                       // swn = (sum of 4 wave-parts acc) / (sum den)
    const int hh = u0 / D_, d = u0 - hh * D_;
    const int w0 = fb * 4;
    const float dn = s_part[w0][hh][0] + s_part[w0+1][hh][0] + s_part[w0+2][hh][0] + s_part[w0+3][hh][0];
    const float ac = s_part[w0][hh][1+d] + s_part[w0+1][hh][1+d] + s_part[w0+2][hh][1+d] + s_part[w0+3][hh][1+d];
    s_swn[fb][hh][d] = ac / dn;
  }
  __syncthreads();
  if (u0 < 136) {                       // agg = bv + Wv·swn
    const int hh = u0 / D_, e = u0 - hh * D_;
    float s = bv[hh*D_ + e];
    #pragma unroll
    for (int d = 0; d < D_; ++d) s = fmaf(Wv[hh*289 + e*D_ + d], s_swn[fb][hh][d], s);
    s_agg[fb][hh*D_ + e] = s;
  }
  __syncthreads();
  if (u0 < 136) {                       // Wo partials: 17 outs x 8 k-parts
    const int o = u0 >> 3, pt = u0 & 7;
    float s = 0.f;
    #pragma unroll
    for (int j = 0; j < D_; ++j) s = fmaf(Wo[o*136 + pt*D_ + j], s_agg[fb][pt*D_ + j], s);
    s_wp[fb][u0] = s;
  }
  __syncthreads();
  if (u0 < D_) {
    float s = bo[u0];
    #pragma unroll
    for (int pt = 0; pt < 8; ++pt) s += s_wp[fb][u0*8 + pt];
    comb[bf*26 + u0] = s;
  } else if (u0 < 26) {
    comb[bf*26 + u0] = x[(size_t)bf * XROW + (u0 - D_)];   // special
  }
}

// ---------------- Kernel 2: LDS-tiled transpose of the two 256x256 W2 ----------------
__global__ __launch_bounds__(256) void transpose_w2_kernel(
    const float* __restrict__ pW2, const float* __restrict__ vW2,
    float* __restrict__ pW2t, float* __restrict__ vW2t)
{
  __shared__ float tile[32][33];
  const int bid = blockIdx.x;           // 128 blocks = 2 matrices x 64 tiles
  const int m = bid >> 6, tid = bid & 63;
  const int ti = (tid >> 3) * 32, tk = (tid & 7) * 32;
  const float* src = m ? vW2 : pW2;
  float* dst = m ? vW2t : pW2t;
  const int tx = threadIdx.x & 31, ty = threadIdx.x >> 5;
  #pragma unroll
  for (int r = 0; r < 4; ++r) tile[ty + 8*r][tx] = src[(ti + ty + 8*r)*HID_ + tk + tx];
  __syncthreads();
  #pragma unroll
  for (int r = 0; r < 4; ++r) dst[(tk + ty + 8*r)*HID_ + ti + tx] = tile[tx][ty + 8*r];
}

// ---------------- Kernel 3: fused policy+value MLPs ----------------
// Grid 512 x 512 threads, 4 batches/block. t = p(1) | kh(1) | i0(7).
// Layer-2: thread owns outputs {i0, i0+128} for k-half kh; cross-half reduce in LDS.
__global__ __launch_bounds__(512) void mlp_kernel(
    const float* __restrict__ comb,
    const float* __restrict__ pW1, const float* __restrict__ pb1,
    const float* __restrict__ pW2t, const float* __restrict__ pb2,
    const float* __restrict__ pW3, const float* __restrict__ pb3,
    const float* __restrict__ vW1, const float* __restrict__ vb1,
    const float* __restrict__ vW2t, const float* __restrict__ vb2,
    const float* __restrict__ vW3, const float* __restrict__ vb3,
    float* __restrict__ out)
{
  __shared__ float s_comb[4][26];
  __shared__ __align__(16) float s_h1[2][4][HID_];
  __shared__ __align__(16) float s_red[2][4][HID_];
  __shared__ __align__(16) float s_h2[2][4][HID_];

  const int t  = threadIdx.x;
  const int b0 = blockIdx.x * 4;
  const int p  = t >> 8;
  const int kh = (t >> 7) & 1;
  const int i0 = t & 127;

  if (t < 104) { const int bb = t / 26, k = t - bb*26; s_comb[bb][k] = comb[(size_t)(b0 + bb)*26 + k]; }
  __syncthreads();

  const float* W1  = p ? vW1  : pW1;   const float* B1 = p ? vb1 : pb1;
  const float* W2t = p ? vW2t : pW2t;  const float* B2 = p ? vb2 : pb2;

  // ---- layer 1: 26 -> 256 (thread owns output i = t&255 for 4 batches)
  {
    const int i = t & 255;
    float a[4] = {0.f, 0.f, 0.f, 0.f};
    const float* wr = W1 + i * 26;
    for (int k = 0; k < 26; ++k) {
      const float wk = wr[k];
      #pragma unroll
      for (int bb = 0; bb < 4; ++bb) a[bb] = fmaf(wk, s_comb[bb][k], a[bb]);
    }
    const float bias = B1[i];
    #pragma unroll
    for (int bb = 0; bb < 4; ++bb) s_h1[p][bb][i] = fmaxf(a[bb] + bias, 0.f);
  }
  __syncthreads();

  // ---- layer 2: 256 -> 256, k-half [kh*128, +128)
  float ac0[4] = {0.f,0.f,0.f,0.f}, ac1[4] = {0.f,0.f,0.f,0.f};
  {
    const int kbase = kh * 128;
    #pragma unroll 2
    for (int k4 = 0; k4 < 32; ++k4) {
      const int k = kbase + 4*k4;
      const float w00 = W2t[(k    )*HID_ + i0      ], w01 = W2t[(k + 1)*HID_ + i0      ];
      const float w02 = W2t[(k + 2)*HID_ + i0      ], w03 = W2t[(k + 3)*HID_ + i0      ];
      const float w10 = W2t[(k    )*HID_ + i0 + 128], w11 = W2t[(k + 1)*HID_ + i0 + 128];
      const float w12 = W2t[(k + 2)*HID_ + i0 + 128], w13 = W2t[(k + 3)*HID_ + i0 + 128];
      #pragma unroll
      for (int bb = 0; bb < 4; ++bb) {
        const float4 hv = *(const float4*)&s_h1[p][bb][k];   // wave-uniform broadcast
        ac0[bb] = fmaf(w00, hv.x, fmaf(w01, hv.y, fmaf(w02, hv.z, fmaf(w03, hv.w, ac0[bb]))));
        ac1[bb] = fmaf(w10, hv.x, fmaf(w11, hv.y, fmaf(w12, hv.z, fmaf(w13, hv.w, ac1[bb]))));
      }
    }
  }
  if (kh == 1) {
    #pragma unroll
    for (int bb = 0; bb < 4; ++bb) {
      s_red[p][bb][i0]       = ac0[bb];
      s_red[p][bb][i0 + 128] = ac1[bb];
    }
  }
  __syncthreads();
  if (kh == 0) {
    const float bi0 = B2[i0], bi1 = B2[i0 + 128];
    #pragma unroll
    for (int bb = 0; bb < 4; ++bb) {
      s_h2[p][bb][i0]       = fmaxf(ac0[bb] + s_red[p][bb][i0]       + bi0, 0.f);
      s_h2[p][bb][i0 + 128] = fmaxf(ac1[bb] + s_red[p][bb][i0 + 128] + bi1, 0.f);
    }
  }
  __syncthreads();

  // ---- layer 3
  if (t < 92) {                         // policy: 4 batches x 23 outputs
    const int bb = t / OUT_, o = t - bb * OUT_;
    const float4* w4 = (const float4*)(pW3 + o * HID_);
    const float4* h4 = (const float4*)&s_h2[0][bb][0];
    float s = pb3[o];
    for (int k = 0; k < 64; ++k) {
      const float4 wv = w4[k], hv = h4[k];
      s = fmaf(wv.x, hv.x, fmaf(wv.y, hv.y, fmaf(wv.z, hv.z, fmaf(wv.w, hv.w, s))));
    }
    out[(size_t)(b0 + bb) * OUT_ + o] = s;
  } else if (t >= 256 && t < 260) {     // value: 4 batches x 1 output
    const int bb = t - 256;
    const float4* w4 = (const float4*)vW3;
    const float4* h4 = (const float4*)&s_h2[1][bb][0];
    float s = vb3[0];
    for (int k = 0; k < 64; ++k) {
      const float4 wv = w4[k], hv = h4[k];
      s = fmaf(wv.x, hv.x, fmaf(wv.y, hv.y, fmaf(wv.z, hv.z, fmaf(wv.w, hv.w, s))));
    }
    out[(size_t)B_ * OUT_ + b0 + bb] = s;
  }
}

extern "C" void kernel_launch(void* const* d_in, const int* in_sizes, int n_in,
                              void* d_out, int out_size, void* d_ws, size_t ws_size,
                              hipStream_t stream) {
  (void)in_sizes; (void)n_in; (void)out_size; (void)ws_size;
  const float* x   = (const float*)d_in[0];
  const float* Wk  = (const float*)d_in[1];
  const float* bk  = (const float*)d_in[2];
  const float* Wv  = (const float*)d_in[3];
  const float* bv  = (const float*)d_in[4];
  const float* q   = (const float*)d_in[5];
  const float* Wo  = (const float*)d_in[6];
  const float* bo  = (const float*)d_in[7];
  const float* pW1 = (const float*)d_in[8];
  const float* pb1 = (const float*)d_in[9];
  const float* pW2 = (const float*)d_in[10];
  const float* pb2 = (const float*)d_in[11];
  const float* pW3 = (const float*)d_in[12];
  const float* pb3 = (const float*)d_in[13];
  const float* vW1 = (const float*)d_in[14];
  const float* vb1 = (const float*)d_in[15];
  const float* vW2 = (const float*)d_in[16];
  const float* vb2 = (const float*)d_in[17];
  const float* vW3 = (const float*)d_in[18];
  const float* vb3 = (const float*)d_in[19];
  float* out = (float*)d_out;

  // workspace: comb (2048*26) | pW2t (65536) | vW2t (65536) floats
  float* comb = (float*)d_ws;
  float* pW2t = comb + (size_t)B_ * 26;
  float* vW2t = pW2t + (size_t)HID_ * HID_;

  transpose_w2_kernel<<<128, 256, 0, stream>>>(pW2, vW2, pW2t, vW2t);
  attn_comb_kernel<<<B_ / 2, 512, 0, stream>>>(x, Wk, bk, Wv, bv, q, Wo, bo, comb);
  mlp_kernel<<<B_ / 4, 512, 0, stream>>>(comb, pW1, pb1, pW2t, pb2, pW3, pb3,
                                         vW1, vb1, vW2t, vb2, vW3, vb3, out);
}

// Round 6
// 55.673 us; speedup vs baseline: 2.4720x; 2.4720x over previous
//
#include <hip/hip_runtime.h>
#include <hip/hip_bf16.h>

#define B_ 2048
#define D_ 17
#define H_ 8
#define HID_ 256
#define OUT_ 23
#define XROW 8721       /* 513*17 floats per batch */

__device__ __forceinline__ float4 ld4u(const float* p) {   // 4B-aligned 16B load
  float4 v; __builtin_memcpy(&v, p, 16); return v;
}

// ---------------- Kernel 1: prep — transpose W2s + fold q into Wk ----------------
// Blocks 0..127: LDS-tiled transpose of pW2/vW2. Block 128: qkc[h*18+d] = sum_e Wk[h,e,d]q[h,e],
// qkc[h*18+17] = bk[h]·q[h].
__global__ __launch_bounds__(256) void prep_kernel(
    const float* __restrict__ pW2, const float* __restrict__ vW2,
    const float* __restrict__ Wk, const float* __restrict__ bk,
    const float* __restrict__ q,
    float* __restrict__ pW2t, float* __restrict__ vW2t, float* __restrict__ qkc)
{
  const int bid = blockIdx.x;
  const int t = threadIdx.x;
  if (bid == 128) {
    if (t < H_ * D_) {
      const int h = t / D_, dd = t - h * D_;
      float s = 0.f;
      #pragma unroll
      for (int e = 0; e < D_; ++e) s = fmaf(Wk[h*289 + e*D_ + dd], q[h*D_ + e], s);
      qkc[h*18 + dd] = s;
    } else if (t < H_ * D_ + H_) {
      const int h = t - H_ * D_;
      float s = 0.f;
      #pragma unroll
      for (int e = 0; e < D_; ++e) s = fmaf(bk[h*D_ + e], q[h*D_ + e], s);
      qkc[h*18 + 17] = s;
    }
    return;
  }
  __shared__ float tile[32][33];
  const int m = bid >> 6, tid = bid & 63;
  const int ti = (tid >> 3) * 32, tk = (tid & 7) * 32;
  const float* src = m ? vW2 : pW2;
  float* dst = m ? vW2t : pW2t;
  const int tx = t & 31, ty = t >> 5;
  #pragma unroll
  for (int r = 0; r < 4; ++r) tile[ty + 8*r][tx] = src[(ti + ty + 8*r)*HID_ + tk + tx];
  __syncthreads();
  #pragma unroll
  for (int r = 0; r < 4; ++r) dst[(tk + ty + 8*r)*HID_ + ti + tx] = tile[tx][ty + 8*r];
}

// ---------------- Kernel 2: register-streaming attention -> comb (B x 26) ----------------
// Block 256 = 4 waves = 1 batch; wave w owns rows [w*128, w*128+128).
// Lane = (head = l&7, rowgroup = l>>3); step covers 8 contiguous rows.
// Monotone mask => ballot early-exit skips dead-tail loads. Double-buffered.
__global__ __launch_bounds__(256, 4) void attn_comb_kernel(
    const float* __restrict__ x,
    const float* __restrict__ qkc,
    const float* __restrict__ Wv, const float* __restrict__ bv,
    const float* __restrict__ Wo, const float* __restrict__ bo,
    float* __restrict__ comb)
{
  __shared__ float s_part[4][H_][18];      // per-wave per-head (den, acc[17])
  __shared__ float s_swn[H_][D_];
  __shared__ float s_agg[H_ * D_];
  __shared__ float s_wp[136];

  const int t = threadIdx.x;
  const int b = blockIdx.x;
  const int w = t >> 6, lane = t & 63;
  const int h = lane & 7, rg = lane >> 3;

  float qk[D_];
  #pragma unroll
  for (int d = 0; d < D_; ++d) qk[d] = qkc[h*18 + d];
  const float chr = qkc[h*18 + 17];

  const float* rb = x + (size_t)b * XROW + D_ + (size_t)(w * 128 + rg) * D_;

  float den = 0.f;
  float acc[D_];
  #pragma unroll
  for (int d = 0; d < D_; ++d) acc[d] = 0.f;

  float4 a0, a1, a2, a3; float a4;     // buffer A
  float4 c0, c1, c2, c3; float c4;     // buffer C

  auto loadA = [&](int S) {
    const float* rp = rb + S * 136;    // step stride = 8 rows * 17
    a0 = ld4u(rp); a1 = ld4u(rp + 4); a2 = ld4u(rp + 8); a3 = ld4u(rp + 12); a4 = rp[16];
  };
  auto loadC = [&](int S) {
    const float* rp = rb + S * 136;
    c0 = ld4u(rp); c1 = ld4u(rp + 4); c2 = ld4u(rp + 8); c3 = ld4u(rp + 12); c4 = rp[16];
  };
  auto comp = [&](const float4& v0, const float4& v1, const float4& v2, const float4& v3, float v4) {
    float sc = chr;
    sc = fmaf(qk[0],  v0.x, sc); sc = fmaf(qk[1],  v0.y, sc);
    sc = fmaf(qk[2],  v0.z, sc); sc = fmaf(qk[3],  v0.w, sc);
    sc = fmaf(qk[4],  v1.x, sc); sc = fmaf(qk[5],  v1.y, sc);
    sc = fmaf(qk[6],  v1.z, sc); sc = fmaf(qk[7],  v1.w, sc);
    sc = fmaf(qk[8],  v2.x, sc); sc = fmaf(qk[9],  v2.y, sc);
    sc = fmaf(qk[10], v2.z, sc); sc = fmaf(qk[11], v2.w, sc);
    sc = fmaf(qk[12], v3.x, sc); sc = fmaf(qk[13], v3.y, sc);
    sc = fmaf(qk[14], v3.z, sc); sc = fmaf(qk[15], v3.w, sc);
    sc = fmaf(qk[16], v4, sc);
    // masked rows are exact zeros; live word0==0 has P~1e-45
    const float p = (v0.x != 0.f) ? __expf(sc) : 0.f;
    den += p;
    acc[0]  = fmaf(p, v0.x, acc[0]);  acc[1]  = fmaf(p, v0.y, acc[1]);
    acc[2]  = fmaf(p, v0.z, acc[2]);  acc[3]  = fmaf(p, v0.w, acc[3]);
    acc[4]  = fmaf(p, v1.x, acc[4]);  acc[5]  = fmaf(p, v1.y, acc[5]);
    acc[6]  = fmaf(p, v1.z, acc[6]);  acc[7]  = fmaf(p, v1.w, acc[7]);
    acc[8]  = fmaf(p, v2.x, acc[8]);  acc[9]  = fmaf(p, v2.y, acc[9]);
    acc[10] = fmaf(p, v2.z, acc[10]); acc[11] = fmaf(p, v2.w, acc[11]);
    acc[12] = fmaf(p, v3.x, acc[12]); acc[13] = fmaf(p, v3.y, acc[13]);
    acc[14] = fmaf(p, v3.z, acc[14]); acc[15] = fmaf(p, v3.w, acc[15]);
    acc[16] = fmaf(p, v4, acc[16]);
  };

  loadA(0);
  #pragma unroll 1
  for (int s = 0; s < 16; s += 2) {
    loadC(s + 1);                                   // prefetch next chunk
    if (__ballot(a0.x != 0.f) == 0ull) break;       // all 8 rows dead -> tail dead
    comp(a0, a1, a2, a3, a4);
    if (s + 2 < 16) loadA(s + 2);
    if (__ballot(c0.x != 0.f) == 0ull) break;
    comp(c0, c1, c2, c3, c4);
  }

  // ---- in-wave reduce over rowgroups (lanes with same head)
  #pragma unroll
  for (int m = 8; m <= 32; m <<= 1) {
    den += __shfl_xor(den, m, 64);
    #pragma unroll
    for (int d = 0; d < D_; ++d) acc[d] += __shfl_xor(acc[d], m, 64);
  }
  if (lane < 8) {
    s_part[w][lane][0] = den;
    #pragma unroll
    for (int d = 0; d < D_; ++d) s_part[w][lane][1 + d] = acc[d];
  }
  __syncthreads();

  // ---- finish (one batch per block)
  if (t < 136) {                        // swn = (sum of 4 wave-part acc) / (sum den)
    const int hh = t / D_, d = t - hh * D_;
    const float dn = s_part[0][hh][0] + s_part[1][hh][0] + s_part[2][hh][0] + s_part[3][hh][0];
    const float ac = s_part[0][hh][1+d] + s_part[1][hh][1+d] + s_part[2][hh][1+d] + s_part[3][hh][1+d];
    s_swn[hh][d] = ac / dn;
  }
  __syncthreads();
  if (t < 136) {                        // agg = bv + Wv·swn
    const int hh = t / D_, e = t - hh * D_;
    float s = bv[hh*D_ + e];
    #pragma unroll
    for (int d = 0; d < D_; ++d) s = fmaf(Wv[hh*289 + e*D_ + d], s_swn[hh][d], s);
    s_agg[hh*D_ + e] = s;
  }
  __syncthreads();
  if (t < 136) {                        // Wo partials: 17 outs x 8 k-parts
    const int o = t >> 3, pt = t & 7;
    float s = 0.f;
    #pragma unroll
    for (int j = 0; j < D_; ++j) s = fmaf(Wo[o*136 + pt*D_ + j], s_agg[pt*D_ + j], s);
    s_wp[t] = s;
  }
  __syncthreads();
  if (t < D_) {
    float s = bo[t];
    #pragma unroll
    for (int pt = 0; pt < 8; ++pt) s += s_wp[t*8 + pt];
    comb[b*26 + t] = s;
  } else if (t < 26) {
    comb[b*26 + t] = x[(size_t)b * XROW + (t - D_)];   // special
  }
}

// ---------------- Kernel 3: fused policy+value MLPs (unchanged from R5) ----------------
__global__ __launch_bounds__(512) void mlp_kernel(
    const float* __restrict__ comb,
    const float* __restrict__ pW1, const float* __restrict__ pb1,
    const float* __restrict__ pW2t, const float* __restrict__ pb2,
    const float* __restrict__ pW3, const float* __restrict__ pb3,
    const float* __restrict__ vW1, const float* __restrict__ vb1,
    const float* __restrict__ vW2t, const float* __restrict__ vb2,
    const float* __restrict__ vW3, const float* __restrict__ vb3,
    float* __restrict__ out)
{
  __shared__ float s_comb[4][26];
  __shared__ __align__(16) float s_h1[2][4][HID_];
  __shared__ __align__(16) float s_red[2][4][HID_];
  __shared__ __align__(16) float s_h2[2][4][HID_];

  const int t  = threadIdx.x;
  const int b0 = blockIdx.x * 4;
  const int p  = t >> 8;
  const int kh = (t >> 7) & 1;
  const int i0 = t & 127;

  if (t < 104) { const int bb = t / 26, k = t - bb*26; s_comb[bb][k] = comb[(size_t)(b0 + bb)*26 + k]; }
  __syncthreads();

  const float* W1  = p ? vW1  : pW1;   const float* B1 = p ? vb1 : pb1;
  const float* W2t = p ? vW2t : pW2t;  const float* B2 = p ? vb2 : pb2;

  // ---- layer 1: 26 -> 256
  {
    const int i = t & 255;
    float a[4] = {0.f, 0.f, 0.f, 0.f};
    const float* wr = W1 + i * 26;
    for (int k = 0; k < 26; ++k) {
      const float wk = wr[k];
      #pragma unroll
      for (int bb = 0; bb < 4; ++bb) a[bb] = fmaf(wk, s_comb[bb][k], a[bb]);
    }
    const float bias = B1[i];
    #pragma unroll
    for (int bb = 0; bb < 4; ++bb) s_h1[p][bb][i] = fmaxf(a[bb] + bias, 0.f);
  }
  __syncthreads();

  // ---- layer 2: 256 -> 256, k-half [kh*128, +128)
  float ac0[4] = {0.f,0.f,0.f,0.f}, ac1[4] = {0.f,0.f,0.f,0.f};
  {
    const int kbase = kh * 128;
    #pragma unroll 2
    for (int k4 = 0; k4 < 32; ++k4) {
      const int k = kbase + 4*k4;
      const float w00 = W2t[(k    )*HID_ + i0      ], w01 = W2t[(k + 1)*HID_ + i0      ];
      const float w02 = W2t[(k + 2)*HID_ + i0      ], w03 = W2t[(k + 3)*HID_ + i0      ];
      const float w10 = W2t[(k    )*HID_ + i0 + 128], w11 = W2t[(k + 1)*HID_ + i0 + 128];
      const float w12 = W2t[(k + 2)*HID_ + i0 + 128], w13 = W2t[(k + 3)*HID_ + i0 + 128];
      #pragma unroll
      for (int bb = 0; bb < 4; ++bb) {
        const float4 hv = *(const float4*)&s_h1[p][bb][k];   // wave-uniform broadcast
        ac0[bb] = fmaf(w00, hv.x, fmaf(w01, hv.y, fmaf(w02, hv.z, fmaf(w03, hv.w, ac0[bb]))));
        ac1[bb] = fmaf(w10, hv.x, fmaf(w11, hv.y, fmaf(w12, hv.z, fmaf(w13, hv.w, ac1[bb]))));
      }
    }
  }
  if (kh == 1) {
    #pragma unroll
    for (int bb = 0; bb < 4; ++bb) {
      s_red[p][bb][i0]       = ac0[bb];
      s_red[p][bb][i0 + 128] = ac1[bb];
    }
  }
  __syncthreads();
  if (kh == 0) {
    const float bi0 = B2[i0], bi1 = B2[i0 + 128];
    #pragma unroll
    for (int bb = 0; bb < 4; ++bb) {
      s_h2[p][bb][i0]       = fmaxf(ac0[bb] + s_red[p][bb][i0]       + bi0, 0.f);
      s_h2[p][bb][i0 + 128] = fmaxf(ac1[bb] + s_red[p][bb][i0 + 128] + bi1, 0.f);
    }
  }
  __syncthreads();

  // ---- layer 3
  if (t < 92) {                         // policy: 4 batches x 23 outputs
    const int bb = t / OUT_, o = t - bb * OUT_;
    const float4* w4 = (const float4*)(pW3 + o * HID_);
    const float4* h4 = (const float4*)&s_h2[0][bb][0];
    float s = pb3[o];
    for (int k = 0; k < 64; ++k) {
      const float4 wv = w4[k], hv = h4[k];
      s = fmaf(wv.x, hv.x, fmaf(wv.y, hv.y, fmaf(wv.z, hv.z, fmaf(wv.w, hv.w, s))));
    }
    out[(size_t)(b0 + bb) * OUT_ + o] = s;
  } else if (t >= 256 && t < 260) {     // value: 4 batches x 1 output
    const int bb = t - 256;
    const float4* w4 = (const float4*)vW3;
    const float4* h4 = (const float4*)&s_h2[1][bb][0];
    float s = vb3[0];
    for (int k = 0; k < 64; ++k) {
      const float4 wv = w4[k], hv = h4[k];
      s = fmaf(wv.x, hv.x, fmaf(wv.y, hv.y, fmaf(wv.z, hv.z, fmaf(wv.w, hv.w, s))));
    }
    out[(size_t)B_ * OUT_ + b0 + bb] = s;
  }
}

extern "C" void kernel_launch(void* const* d_in, const int* in_sizes, int n_in,
                              void* d_out, int out_size, void* d_ws, size_t ws_size,
                              hipStream_t stream) {
  (void)in_sizes; (void)n_in; (void)out_size; (void)ws_size;
  const float* x   = (const float*)d_in[0];
  const float* Wk  = (const float*)d_in[1];
  const float* bk  = (const float*)d_in[2];
  const float* Wv  = (const float*)d_in[3];
  const float* bv  = (const float*)d_in[4];
  const float* q   = (const float*)d_in[5];
  const float* Wo  = (const float*)d_in[6];
  const float* bo  = (const float*)d_in[7];
  const float* pW1 = (const float*)d_in[8];
  const float* pb1 = (const float*)d_in[9];
  const float* pW2 = (const float*)d_in[10];
  const float* pb2 = (const float*)d_in[11];
  const float* pW3 = (const float*)d_in[12];
  const float* pb3 = (const float*)d_in[13];
  const float* vW1 = (const float*)d_in[14];
  const float* vb1 = (const float*)d_in[15];
  const float* vW2 = (const float*)d_in[16];
  const float* vb2 = (const float*)d_in[17];
  const float* vW3 = (const float*)d_in[18];
  const float* vb3 = (const float*)d_in[19];
  float* out = (float*)d_out;

  // workspace: comb (2048*26) | pW2t (65536) | vW2t (65536) | qkc (144) floats
  float* comb = (float*)d_ws;
  float* pW2t = comb + (size_t)B_ * 26;
  float* vW2t = pW2t + (size_t)HID_ * HID_;
  float* qkc  = vW2t + (size_t)HID_ * HID_;

  prep_kernel<<<129, 256, 0, stream>>>(pW2, vW2, Wk, bk, q, pW2t, vW2t, qkc);
  attn_comb_kernel<<<B_, 256, 0, stream>>>(x, qkc, Wv, bv, Wo, bo, comb);
  mlp_kernel<<<B_ / 4, 512, 0, stream>>>(comb, pW1, pb1, pW2t, pb2, pW3, pb3,
                                         vW1, vb1, vW2t, vb2, vW3, vb3, out);
}